// Round 1
// baseline (69.586 us; speedup 1.0000x reference)
//
#include <hip/hip_runtime.h>

// Volumetric (NeRF) renderer: one 64-lane wave per ray, S=192 samples in
// 3 chunks of 64. Exclusive cumprod of (1-alpha+1e-10) via wave scan.

#define NUM_S 192

__global__ __launch_bounds__(256) void volrend_kernel(
    const float* __restrict__ dens,   // [R, S]
    const float* __restrict__ cols,   // [R, S, 3]
    const float* __restrict__ tv,     // [R, S]
    const float* __restrict__ rdir,   // [R, 3]
    float* __restrict__ out_rgb,      // [R, 3]
    float* __restrict__ out_depth,    // [R]
    float* __restrict__ out_w,        // [R, S]
    float* __restrict__ out_alpha,    // [R, S]
    float* __restrict__ out_acc,      // [R]
    int R)
{
    const int wid  = (blockIdx.x * blockDim.x + threadIdx.x) >> 6; // ray id
    const int lane = threadIdx.x & 63;
    if (wid >= R) return;
    const int r = wid;

    // ray direction norm
    const float dx = rdir[r * 3 + 0];
    const float dy = rdir[r * 3 + 1];
    const float dz = rdir[r * 3 + 2];
    const float nrm = sqrtf(dx * dx + dy * dy + dz * dz);

    float carry = 1.0f;   // transmittance product carried across chunks
    float acc_r = 0.0f, acc_g = 0.0f, acc_b = 0.0f;
    float acc_d = 0.0f, acc_w = 0.0f;

    const long base = (long)r * NUM_S;

    #pragma unroll
    for (int c = 0; c < 3; ++c) {
        const int s = c * 64 + lane;
        const float t = tv[base + s];

        // dist = t[s+1] - t[s]; last sample -> 1e10
        float tn = __shfl_down(t, 1);          // lane 63 garbage, patched below
        float dist;
        if (s == NUM_S - 1) {
            dist = 1e10f;
        } else if (lane == 63) {
            dist = tv[base + s + 1] - t;       // crosses chunk boundary
        } else {
            dist = tn - t;
        }
        dist *= nrm;

        const float d = dens[base + s];
        const float a = 1.0f - __expf(-fmaxf(d, 0.0f) * dist);
        float f = 1.0f - a + 1e-10f;

        // inclusive cumprod scan across 64 lanes
        float p = f;
        #pragma unroll
        for (int off = 1; off < 64; off <<= 1) {
            float q = __shfl_up(p, off);
            if (lane >= off) p *= q;
        }
        // exclusive transmittance
        float excl = __shfl_up(p, 1);
        float trans = carry * ((lane == 0) ? 1.0f : excl);

        const float w = a * trans;
        out_w[base + s]     = w;
        out_alpha[base + s] = a;

        const long cb = (base + s) * 3;
        acc_r += w * cols[cb + 0];
        acc_g += w * cols[cb + 1];
        acc_b += w * cols[cb + 2];
        acc_d += w * t;
        acc_w += w;

        carry *= __shfl(p, 63);   // chunk-total product broadcast
    }

    // wave reduction (64 lanes) for the per-ray scalars
    #pragma unroll
    for (int off = 32; off > 0; off >>= 1) {
        acc_r += __shfl_down(acc_r, off);
        acc_g += __shfl_down(acc_g, off);
        acc_b += __shfl_down(acc_b, off);
        acc_d += __shfl_down(acc_d, off);
        acc_w += __shfl_down(acc_w, off);
    }
    if (lane == 0) {
        out_rgb[r * 3 + 0] = acc_r;
        out_rgb[r * 3 + 1] = acc_g;
        out_rgb[r * 3 + 2] = acc_b;
        out_depth[r] = acc_d;
        out_acc[r]   = acc_w;
    }
}

extern "C" void kernel_launch(void* const* d_in, const int* in_sizes, int n_in,
                              void* d_out, int out_size, void* d_ws, size_t ws_size,
                              hipStream_t stream) {
    const float* dens = (const float*)d_in[0];  // [R,S]
    const float* cols = (const float*)d_in[1];  // [R,S,3]
    const float* tv   = (const float*)d_in[2];  // [R,S]
    const float* rdir = (const float*)d_in[3];  // [R,3]

    const int R = in_sizes[3] / 3;
    // output layout: rgb[R,3] | depth[R] | weights[R,S] | alpha[R,S] | acc[R]
    float* out       = (float*)d_out;
    float* out_rgb   = out;
    float* out_depth = out_rgb + (long)R * 3;
    float* out_w     = out_depth + R;
    float* out_alpha = out_w + (long)R * NUM_S;
    float* out_acc   = out_alpha + (long)R * NUM_S;

    const int threads = 256;                 // 4 waves -> 4 rays per block
    const int rays_per_block = threads / 64;
    const int blocks = (R + rays_per_block - 1) / rays_per_block;
    volrend_kernel<<<blocks, threads, 0, stream>>>(
        dens, cols, tv, rdir, out_rgb, out_depth, out_w, out_alpha, out_acc, R);
}

// Round 2
// 69.174 us; speedup vs baseline: 1.0059x; 1.0059x over previous
//
#include <hip/hip_runtime.h>

// Volumetric (NeRF) renderer: one 64-lane wave per ray, S=192 samples in
// 3 chunks of 64. All three chunk scans run interleaved (ILP) instead of
// serially chained through a carry.

#define NUM_S 192

__global__ __launch_bounds__(256) void volrend_kernel(
    const float* __restrict__ dens,   // [R, S]
    const float* __restrict__ cols,   // [R, S, 3]
    const float* __restrict__ tv,     // [R, S]
    const float* __restrict__ rdir,   // [R, 3]
    float* __restrict__ out_rgb,      // [R, 3]
    float* __restrict__ out_depth,    // [R]
    float* __restrict__ out_w,        // [R, S]
    float* __restrict__ out_alpha,    // [R, S]
    float* __restrict__ out_acc,      // [R]
    int R)
{
    const int wid  = (blockIdx.x * blockDim.x + threadIdx.x) >> 6; // ray id
    const int lane = threadIdx.x & 63;
    if (wid >= R) return;
    const int r = wid;

    const long base = (long)r * NUM_S;

    // ---- issue ALL global loads up front (latency overlap) ----
    const float t0 = tv[base + lane];
    const float t1 = tv[base + 64 + lane];
    const float t2 = tv[base + 128 + lane];
    const float d0 = dens[base + lane];
    const float d1 = dens[base + 64 + lane];
    const float d2 = dens[base + 128 + lane];

    const long cb0 = (base + lane) * 3;
    const long cb1 = (base + 64 + lane) * 3;
    const long cb2 = (base + 128 + lane) * 3;
    const float c0r = cols[cb0 + 0], c0g = cols[cb0 + 1], c0b = cols[cb0 + 2];
    const float c1r = cols[cb1 + 0], c1g = cols[cb1 + 1], c1b = cols[cb1 + 2];
    const float c2r = cols[cb2 + 0], c2g = cols[cb2 + 1], c2b = cols[cb2 + 2];

    const float dx = rdir[r * 3 + 0];
    const float dy = rdir[r * 3 + 1];
    const float dz = rdir[r * 3 + 2];
    const float nrm = sqrtf(dx * dx + dy * dy + dz * dz);

    // ---- dists: t[s+1]-t[s], last = 1e10; chunk boundaries via broadcast ----
    float tn0 = __shfl_down(t0, 1);
    float tn1 = __shfl_down(t1, 1);
    float tn2 = __shfl_down(t2, 1);
    const float b1 = __shfl(t1, 0);   // first t of chunk 1
    const float b2 = __shfl(t2, 0);   // first t of chunk 2
    if (lane == 63) { tn0 = b1; tn1 = b2; tn2 = t2 + 1e10f; }

    const float dist0 = (tn0 - t0) * nrm;
    const float dist1 = (tn1 - t1) * nrm;
    const float dist2 = (tn2 - t2) * nrm;

    const float a0 = 1.0f - __expf(-fmaxf(d0, 0.0f) * dist0);
    const float a1 = 1.0f - __expf(-fmaxf(d1, 0.0f) * dist1);
    const float a2 = 1.0f - __expf(-fmaxf(d2, 0.0f) * dist2);

    // ---- three independent inclusive cumprod scans, interleaved ----
    float p0 = 1.0f - a0 + 1e-10f;
    float p1 = 1.0f - a1 + 1e-10f;
    float p2 = 1.0f - a2 + 1e-10f;
    #pragma unroll
    for (int off = 1; off < 64; off <<= 1) {
        const float q0 = __shfl_up(p0, off);
        const float q1 = __shfl_up(p1, off);
        const float q2 = __shfl_up(p2, off);
        if (lane >= off) { p0 *= q0; p1 *= q1; p2 *= q2; }
    }
    const float tot0 = __shfl(p0, 63);
    const float tot1 = __shfl(p1, 63);

    float e0 = __shfl_up(p0, 1);
    float e1 = __shfl_up(p1, 1);
    float e2 = __shfl_up(p2, 1);
    if (lane == 0) { e0 = 1.0f; e1 = 1.0f; e2 = 1.0f; }

    const float tr0 = e0;
    const float tr1 = tot0 * e1;
    const float tr2 = tot0 * tot1 * e2;

    const float w0 = a0 * tr0;
    const float w1 = a1 * tr1;
    const float w2 = a2 * tr2;

    out_w[base + lane]           = w0;
    out_w[base + 64 + lane]      = w1;
    out_w[base + 128 + lane]     = w2;
    out_alpha[base + lane]       = a0;
    out_alpha[base + 64 + lane]  = a1;
    out_alpha[base + 128 + lane] = a2;

    // ---- per-ray reductions ----
    float acc_r = w0 * c0r + w1 * c1r + w2 * c2r;
    float acc_g = w0 * c0g + w1 * c1g + w2 * c2g;
    float acc_b = w0 * c0b + w1 * c1b + w2 * c2b;
    float acc_d = w0 * t0 + w1 * t1 + w2 * t2;
    float acc_w = w0 + w1 + w2;

    #pragma unroll
    for (int off = 32; off > 0; off >>= 1) {
        acc_r += __shfl_xor(acc_r, off);
        acc_g += __shfl_xor(acc_g, off);
        acc_b += __shfl_xor(acc_b, off);
        acc_d += __shfl_xor(acc_d, off);
        acc_w += __shfl_xor(acc_w, off);
    }
    if (lane == 0) {
        out_rgb[r * 3 + 0] = acc_r;
        out_rgb[r * 3 + 1] = acc_g;
        out_rgb[r * 3 + 2] = acc_b;
        out_depth[r] = acc_d;
        out_acc[r]   = acc_w;
    }
}

extern "C" void kernel_launch(void* const* d_in, const int* in_sizes, int n_in,
                              void* d_out, int out_size, void* d_ws, size_t ws_size,
                              hipStream_t stream) {
    const float* dens = (const float*)d_in[0];  // [R,S]
    const float* cols = (const float*)d_in[1];  // [R,S,3]
    const float* tv   = (const float*)d_in[2];  // [R,S]
    const float* rdir = (const float*)d_in[3];  // [R,3]

    const int R = in_sizes[3] / 3;
    // output layout: rgb[R,3] | depth[R] | weights[R,S] | alpha[R,S] | acc[R]
    float* out       = (float*)d_out;
    float* out_rgb   = out;
    float* out_depth = out_rgb + (long)R * 3;
    float* out_w     = out_depth + R;
    float* out_alpha = out_w + (long)R * NUM_S;
    float* out_acc   = out_alpha + (long)R * NUM_S;

    const int threads = 256;                 // 4 waves -> 4 rays per block
    const int rays_per_block = threads / 64;
    const int blocks = (R + rays_per_block - 1) / rays_per_block;
    volrend_kernel<<<blocks, threads, 0, stream>>>(
        dens, cols, tv, rdir, out_rgb, out_depth, out_w, out_alpha, out_acc, R);
}

// Round 3
// 68.712 us; speedup vs baseline: 1.0127x; 1.0067x over previous
//
#include <hip/hip_runtime.h>

// Volumetric (NeRF) renderer. One 64-lane wave per ray, each lane owns 3
// CONSECUTIVE samples (s = 3*lane .. 3*lane+2). Single wave-scan over
// per-lane products; vectorized 12B loads/stores.

#define NUM_S 192

struct f3 { float x, y, z; };   // 12B, align(4) -> global_load_dwordx3

__global__ __launch_bounds__(256) void volrend_kernel(
    const float* __restrict__ dens,   // [R, S]
    const float* __restrict__ cols,   // [R, S, 3]
    const float* __restrict__ tv,     // [R, S]
    const float* __restrict__ rdir,   // [R, 3]
    float* __restrict__ out_rgb,      // [R, 3]
    float* __restrict__ out_depth,    // [R]
    float* __restrict__ out_w,        // [R, S]
    float* __restrict__ out_alpha,    // [R, S]
    float* __restrict__ out_acc,      // [R]
    int R)
{
    const int wid  = (blockIdx.x * blockDim.x + threadIdx.x) >> 6; // ray id
    const int lane = threadIdx.x & 63;
    if (wid >= R) return;

    const long base = (long)wid * NUM_S;
    const int  s0   = 3 * lane;

    // ---- vector loads: lane owns samples 3l..3l+2 ----
    const f3 t  = *(const f3*)(tv   + base + s0);
    const f3 d  = *(const f3*)(dens + base + s0);
    const float* cp = cols + (base + s0) * 3;
    const f3 c0 = *(const f3*)(cp + 0);
    const f3 c1 = *(const f3*)(cp + 3);
    const f3 c2 = *(const f3*)(cp + 6);
    const f3 rd = *(const f3*)(rdir + (long)wid * 3);

    const float nrm = sqrtf(rd.x * rd.x + rd.y * rd.y + rd.z * rd.z);

    // ---- dists ----
    const float tnext = __shfl_down(t.x, 1);     // t[3l+3] (lane63 unused)
    const float dist0 = (t.y - t.x) * nrm;
    const float dist1 = (t.z - t.y) * nrm;
    const float dist2 = (lane == 63) ? 1e10f * nrm : (tnext - t.z) * nrm;

    const float a0 = 1.0f - __expf(-fmaxf(d.x, 0.0f) * dist0);
    const float a1 = 1.0f - __expf(-fmaxf(d.y, 0.0f) * dist1);
    const float a2 = 1.0f - __expf(-fmaxf(d.z, 0.0f) * dist2);

    const float f0 = 1.0f - a0 + 1e-10f;
    const float f1 = 1.0f - a1 + 1e-10f;
    const float f2 = 1.0f - a2 + 1e-10f;
    const float f01 = f0 * f1;

    // ---- single inclusive scan over per-lane products ----
    float P = f01 * f2;
    #pragma unroll
    for (int off = 1; off < 64; off <<= 1) {
        const float q = __shfl_up(P, off);
        if (lane >= off) P *= q;
    }
    float excl = __shfl_up(P, 1);
    if (lane == 0) excl = 1.0f;

    const float w0 = a0 * excl;
    const float w1 = a1 * excl * f0;
    const float w2 = a2 * excl * f01;

    // ---- coalesced 12B stores ----
    f3 wv; wv.x = w0; wv.y = w1; wv.z = w2;
    f3 av; av.x = a0; av.y = a1; av.z = a2;
    *(f3*)(out_w     + base + s0) = wv;
    *(f3*)(out_alpha + base + s0) = av;

    // ---- per-ray reductions ----
    float acc_r = w0 * c0.x + w1 * c1.x + w2 * c2.x;
    float acc_g = w0 * c0.y + w1 * c1.y + w2 * c2.y;
    float acc_b = w0 * c0.z + w1 * c1.z + w2 * c2.z;
    float acc_d = w0 * t.x + w1 * t.y + w2 * t.z;
    float acc_w = w0 + w1 + w2;

    #pragma unroll
    for (int off = 32; off > 0; off >>= 1) {
        acc_r += __shfl_xor(acc_r, off);
        acc_g += __shfl_xor(acc_g, off);
        acc_b += __shfl_xor(acc_b, off);
        acc_d += __shfl_xor(acc_d, off);
        acc_w += __shfl_xor(acc_w, off);
    }
    if (lane == 0) {
        f3 rgb; rgb.x = acc_r; rgb.y = acc_g; rgb.z = acc_b;
        *(f3*)(out_rgb + (long)wid * 3) = rgb;
        out_depth[wid] = acc_d;
        out_acc[wid]   = acc_w;
    }
}

extern "C" void kernel_launch(void* const* d_in, const int* in_sizes, int n_in,
                              void* d_out, int out_size, void* d_ws, size_t ws_size,
                              hipStream_t stream) {
    const float* dens = (const float*)d_in[0];  // [R,S]
    const float* cols = (const float*)d_in[1];  // [R,S,3]
    const float* tv   = (const float*)d_in[2];  // [R,S]
    const float* rdir = (const float*)d_in[3];  // [R,3]

    const int R = in_sizes[3] / 3;
    // output layout: rgb[R,3] | depth[R] | weights[R,S] | alpha[R,S] | acc[R]
    float* out       = (float*)d_out;
    float* out_rgb   = out;
    float* out_depth = out_rgb + (long)R * 3;
    float* out_w     = out_depth + R;
    float* out_alpha = out_w + (long)R * NUM_S;
    float* out_acc   = out_alpha + (long)R * NUM_S;

    const int threads = 256;                 // 4 waves -> 4 rays per block
    const int rays_per_block = threads / 64;
    const int blocks = (R + rays_per_block - 1) / rays_per_block;
    volrend_kernel<<<blocks, threads, 0, stream>>>(
        dens, cols, tv, rdir, out_rgb, out_depth, out_w, out_alpha, out_acc, R);
}

// Round 4
// 56.042 us; speedup vs baseline: 1.2417x; 1.2261x over previous
//
#include <hip/hip_runtime.h>

// Volumetric (NeRF) renderer: one 64-lane wave per ray, S=192 samples in
// 3 chunks of 64 (lane <-> sample c*64+lane). Non-temporal stores for the
// big weights/alpha outputs so the ~252 MB input set stays resident in the
// 256 MB Infinity Cache across graph replays.

#define NUM_S 192

__global__ __launch_bounds__(256) void volrend_kernel(
    const float* __restrict__ dens,   // [R, S]
    const float* __restrict__ cols,   // [R, S, 3]
    const float* __restrict__ tv,     // [R, S]
    const float* __restrict__ rdir,   // [R, 3]
    float* __restrict__ out_rgb,      // [R, 3]
    float* __restrict__ out_depth,    // [R]
    float* __restrict__ out_w,        // [R, S]
    float* __restrict__ out_alpha,    // [R, S]
    float* __restrict__ out_acc,      // [R]
    int R)
{
    const int wid  = (blockIdx.x * blockDim.x + threadIdx.x) >> 6; // ray id
    const int lane = threadIdx.x & 63;
    if (wid >= R) return;
    const int r = wid;

    const long base = (long)r * NUM_S;

    // ---- issue ALL global loads up front (latency overlap) ----
    const float t0 = tv[base + lane];
    const float t1 = tv[base + 64 + lane];
    const float t2 = tv[base + 128 + lane];
    const float d0 = dens[base + lane];
    const float d1 = dens[base + 64 + lane];
    const float d2 = dens[base + 128 + lane];

    const long cb0 = (base + lane) * 3;
    const long cb1 = (base + 64 + lane) * 3;
    const long cb2 = (base + 128 + lane) * 3;
    const float c0r = cols[cb0 + 0], c0g = cols[cb0 + 1], c0b = cols[cb0 + 2];
    const float c1r = cols[cb1 + 0], c1g = cols[cb1 + 1], c1b = cols[cb1 + 2];
    const float c2r = cols[cb2 + 0], c2g = cols[cb2 + 1], c2b = cols[cb2 + 2];

    const float dx = rdir[r * 3 + 0];
    const float dy = rdir[r * 3 + 1];
    const float dz = rdir[r * 3 + 2];
    const float nrm = sqrtf(dx * dx + dy * dy + dz * dz);

    // ---- dists: t[s+1]-t[s], last = 1e10; chunk boundaries via broadcast ----
    float tn0 = __shfl_down(t0, 1);
    float tn1 = __shfl_down(t1, 1);
    float tn2 = __shfl_down(t2, 1);
    const float b1 = __shfl(t1, 0);   // first t of chunk 1
    const float b2 = __shfl(t2, 0);   // first t of chunk 2
    if (lane == 63) { tn0 = b1; tn1 = b2; tn2 = t2 + 1e10f; }

    const float dist0 = (tn0 - t0) * nrm;
    const float dist1 = (tn1 - t1) * nrm;
    const float dist2 = (tn2 - t2) * nrm;

    const float a0 = 1.0f - __expf(-fmaxf(d0, 0.0f) * dist0);
    const float a1 = 1.0f - __expf(-fmaxf(d1, 0.0f) * dist1);
    const float a2 = 1.0f - __expf(-fmaxf(d2, 0.0f) * dist2);

    // ---- three independent inclusive cumprod scans, interleaved ----
    float p0 = 1.0f - a0 + 1e-10f;
    float p1 = 1.0f - a1 + 1e-10f;
    float p2 = 1.0f - a2 + 1e-10f;
    #pragma unroll
    for (int off = 1; off < 64; off <<= 1) {
        const float q0 = __shfl_up(p0, off);
        const float q1 = __shfl_up(p1, off);
        const float q2 = __shfl_up(p2, off);
        if (lane >= off) { p0 *= q0; p1 *= q1; p2 *= q2; }
    }
    const float tot0 = __shfl(p0, 63);
    const float tot1 = __shfl(p1, 63);

    float e0 = __shfl_up(p0, 1);
    float e1 = __shfl_up(p1, 1);
    float e2 = __shfl_up(p2, 1);
    if (lane == 0) { e0 = 1.0f; e1 = 1.0f; e2 = 1.0f; }

    const float tr0 = e0;
    const float tr1 = tot0 * e1;
    const float tr2 = tot0 * tot1 * e2;

    const float w0 = a0 * tr0;
    const float w1 = a1 * tr1;
    const float w2 = a2 * tr2;

    // ---- non-temporal (no cache-allocate) dense stores for big outputs ----
    __builtin_nontemporal_store(w0, out_w + base + lane);
    __builtin_nontemporal_store(w1, out_w + base + 64 + lane);
    __builtin_nontemporal_store(w2, out_w + base + 128 + lane);
    __builtin_nontemporal_store(a0, out_alpha + base + lane);
    __builtin_nontemporal_store(a1, out_alpha + base + 64 + lane);
    __builtin_nontemporal_store(a2, out_alpha + base + 128 + lane);

    // ---- per-ray reductions ----
    float acc_r = w0 * c0r + w1 * c1r + w2 * c2r;
    float acc_g = w0 * c0g + w1 * c1g + w2 * c2g;
    float acc_b = w0 * c0b + w1 * c1b + w2 * c2b;
    float acc_d = w0 * t0 + w1 * t1 + w2 * t2;
    float acc_w = w0 + w1 + w2;

    #pragma unroll
    for (int off = 32; off > 0; off >>= 1) {
        acc_r += __shfl_xor(acc_r, off);
        acc_g += __shfl_xor(acc_g, off);
        acc_b += __shfl_xor(acc_b, off);
        acc_d += __shfl_xor(acc_d, off);
        acc_w += __shfl_xor(acc_w, off);
    }
    if (lane == 0) {
        out_rgb[r * 3 + 0] = acc_r;
        out_rgb[r * 3 + 1] = acc_g;
        out_rgb[r * 3 + 2] = acc_b;
        out_depth[r] = acc_d;
        out_acc[r]   = acc_w;
    }
}

extern "C" void kernel_launch(void* const* d_in, const int* in_sizes, int n_in,
                              void* d_out, int out_size, void* d_ws, size_t ws_size,
                              hipStream_t stream) {
    const float* dens = (const float*)d_in[0];  // [R,S]
    const float* cols = (const float*)d_in[1];  // [R,S,3]
    const float* tv   = (const float*)d_in[2];  // [R,S]
    const float* rdir = (const float*)d_in[3];  // [R,3]

    const int R = in_sizes[3] / 3;
    // output layout: rgb[R,3] | depth[R] | weights[R,S] | alpha[R,S] | acc[R]
    float* out       = (float*)d_out;
    float* out_rgb   = out;
    float* out_depth = out_rgb + (long)R * 3;
    float* out_w     = out_depth + R;
    float* out_alpha = out_w + (long)R * NUM_S;
    float* out_acc   = out_alpha + (long)R * NUM_S;

    const int threads = 256;                 // 4 waves -> 4 rays per block
    const int rays_per_block = threads / 64;
    const int blocks = (R + rays_per_block - 1) / rays_per_block;
    volrend_kernel<<<blocks, threads, 0, stream>>>(
        dens, cols, tv, rdir, out_rgb, out_depth, out_w, out_alpha, out_acc, R);
}